// Round 5
// baseline (124.084 us; speedup 1.0000x reference)
//
#include <hip/hip_runtime.h>
#include <hip/hip_bf16.h>
#include <math.h>

// ---------------------------------------------------------------------------
// Metric loss (lifted structure) on MI355X — R8: MEASUREMENT ROUND.
// R3/R6/R7 all land at 99.6-101.4us despite major structural changes
// (launch count, reg caps, K-loop pipelining). Our kernels are invisible in
// the profile (all < the 42us harness fill dispatches that fill top-5), so
// egemm's true cost is unknown (model says ~10-15us; residual says ~40+).
// This round runs the egemm Gram 3x (24 flattened K-steps into the same acc,
// epilogue scales by 1/3; ~1e-5 loss perturbation vs 6.68 threshold):
//   * delta(dur) vs ~100.5 = 2 x egemm_cost  (pre-committed readout)
//   * if egemm_cost > 25us, the 3x kernel (>75us) enters top-5 WITH counters
// Everything else identical to R7.
// ---------------------------------------------------------------------------

typedef __bf16 bf16x8 __attribute__((ext_vector_type(8)));
typedef float floatx4 __attribute__((ext_vector_type(4)));

#define KD 256
#define NU 6144
#define NBU 48
#define TU (NBU * (NBU + 1) / 2) /* 1176 */
#define BM 128
#define BK 32
#define ECONST 2.718281828459045f
#define GRAM_REPS 3 /* measurement: Gram computed 3x, result scaled by 1/3 */

// logical (row r, 16B k-slot q) -> bf16 element index in swizzled LDS tile
#define LSLOT(r, q) ((((r) * 4 + ((q) ^ (((r) >> 1) & 3)))) * 8)

__device__ __forceinline__ void gload_lds16(const void* g, void* l) {
  __builtin_amdgcn_global_load_lds((const __attribute__((address_space(1))) unsigned int*)g,
                                   (__attribute__((address_space(3))) unsigned int*)l,
                                   16, 0, 0);
}

// ---- prep: bf16 convert unique rows, row sq from bf16; zero accums + out ---
__global__ __launch_bounds__(256) void prep_kernel(const float* __restrict__ text,
                                                   const float* __restrict__ shape,
                                                   __bf16* __restrict__ Xu,
                                                   float* __restrict__ sq,
                                                   float* __restrict__ rowacc,
                                                   float* __restrict__ out, int out_n) {
  int gt = blockIdx.x * 256 + threadIdx.x;
  if (gt < 2 * NU) rowacc[gt] = 0.f;  // St ++ Ss contiguous
  if (gt < out_n) out[gt] = 0.f;      // loss kernel atomicAdds into out[0]
  int wave = gt >> 6;                 // one wave per unique row, 0..6143
  int lane = gt & 63;
  const float* src = (wave < 4096) ? (text + (size_t)wave * KD)
                                   : (shape + (size_t)(wave - 4096) * KD);
  // one float4 per lane = the whole 256-float row per wave
  float4 v = ((const float4*)src)[lane];
  __bf16 h0 = (__bf16)v.x, h1 = (__bf16)v.y, h2 = (__bf16)v.z, h3 = (__bf16)v.w;
  union { __bf16 h[4]; ushort2 u2[2]; } pk;
  pk.h[0] = h0; pk.h[1] = h1; pk.h[2] = h2; pk.h[3] = h3;
  ((ushort2*)(Xu + (size_t)wave * KD))[lane * 2] = pk.u2[0];
  ((ushort2*)(Xu + (size_t)wave * KD))[lane * 2 + 1] = pk.u2[1];
  // square the ROUNDED values (consistency with MFMA G)
  float f0 = (float)h0, f1 = (float)h1, f2 = (float)h2, f3 = (float)h3;
  float s = f0 * f0 + f1 * f1 + f2 * f2 + f3 * f3;
#pragma unroll
  for (int m = 1; m < 64; m <<= 1) s += __shfl_xor(s, m, 64);
  if (lane == 0) sq[wave] = s;
}

// ---- triangular Gram + E + diag-free row/col partial sums ------------------
// (256,3): 170-VGPR cap; LDS 34KB -> 3 blocks/CU.
__global__ __launch_bounds__(256, 3) void egemm_tri_kernel(
    const __bf16* __restrict__ X, const float* __restrict__ sq,
    float* __restrict__ rowacc) {  // [0,NU)=St, [NU,2NU)=Ss
  __shared__ __align__(16) __bf16 As[2][BM * BK];
  __shared__ __align__(16) __bf16 Bs[2][BM * BK];
  __shared__ float rowbuf[2][128];
  __shared__ float colbuf[2][128];

  // triangular decode: by >= bx
  int t = blockIdx.x;
  int by = (int)((sqrtf(8.0f * (float)t + 1.0f) - 1.0f) * 0.5f);
  while ((by + 1) * (by + 2) / 2 <= t) ++by;
  while (by * (by + 1) / 2 > t) --by;
  const int bx = t - by * (by + 1) / 2;

  const int mBase = by * BM;  // rows (mBase >= nBase)
  const int nBase = bx * BM;  // cols
  const bool diag = (by == bx);

  const int tid = threadIdx.x;
  const int lane = tid & 63;
  const int w = tid >> 6;  // 2x2 wave grid of 64x64 tiles
  const int warpM = w >> 1, warpN = w & 1;
  const int quad = lane >> 4;
  const int l15 = lane & 15;

  floatx4 acc[4][4] = {};

  // staging: chunk c (16 rows, 1KB); lane L -> row 16c+(L>>2), swizzled k-slot
  const int sRow = lane >> 2;
  const int sCol = (((lane & 3) ^ ((lane >> 3) & 3))) * 8;

  // 2-phase pipeline (one s_barrier per K-step; stage(t+1) after the barrier
  // hides under compute(t)).  MEASUREMENT: 24 steps = 3 identical Gram passes
  // accumulated into acc (no DCE possible: acc feeds the epilogue); epilogue
  // scales by 1/3.
#define STAGE(b, kt)                                                                   \
  {                                                                                    \
    _Pragma("unroll") for (int h = 0; h < 2; ++h) {                                    \
      int c = h * 4 + w;                                                               \
      gload_lds16(X + (size_t)(mBase + c * 16 + sRow) * KD + (kt) + sCol,              \
                  &As[b][c * 512]);                                                    \
      gload_lds16(X + (size_t)(nBase + c * 16 + sRow) * KD + (kt) + sCol,              \
                  &Bs[b][c * 512]);                                                    \
    }                                                                                  \
  }

  const int NSTEP = GRAM_REPS * (KD / BK);  // 24
  STAGE(0, 0);
  for (int s = 0; s < NSTEP; ++s) {
    const int cur = s & 1;
    asm volatile("s_waitcnt vmcnt(0)" ::: "memory");
    __builtin_amdgcn_s_barrier();
    asm volatile("" ::: "memory");
    if (s < NSTEP - 1) STAGE(cur ^ 1, ((s + 1) & 7) * BK);

    bf16x8 af[4], bfr[4];
#pragma unroll
    for (int tm = 0; tm < 4; ++tm)
      af[tm] = *(const bf16x8*)&As[cur][LSLOT(warpM * 64 + tm * 16 + l15, quad)];
#pragma unroll
    for (int tn = 0; tn < 4; ++tn)
      bfr[tn] = *(const bf16x8*)&Bs[cur][LSLOT(warpN * 64 + tn * 16 + l15, quad)];
#pragma unroll
    for (int tm = 0; tm < 4; ++tm)
#pragma unroll
      for (int tn = 0; tn < 4; ++tn)
        acc[tm][tn] = __builtin_amdgcn_mfma_f32_16x16x32_bf16(af[tm], bfr[tn], acc[tm][tn], 0, 0, 0);
  }
#undef STAGE

  // ---- epilogue: E = exp(1-D), diag-free row+col sums ----
  const int rbase = mBase + warpM * 64;
  const int cbase = nBase + warpN * 64;
  float sqr[4][4], sqc[4];
#pragma unroll
  for (int tm = 0; tm < 4; ++tm)
#pragma unroll
    for (int r = 0; r < 4; ++r)
      sqr[tm][r] = sq[rbase + tm * 16 + quad * 4 + r];
#pragma unroll
  for (int tn = 0; tn < 4; ++tn)
    sqc[tn] = sq[cbase + tn * 16 + l15];

  const float L2E = 1.44269504088896f;
  const float RSCL = 1.0f / (float)GRAM_REPS;
  float cs[4] = {0.f, 0.f, 0.f, 0.f};
#pragma unroll
  for (int tm = 0; tm < 4; ++tm) {
    float rs[4] = {0.f, 0.f, 0.f, 0.f};
#pragma unroll
    for (int tn = 0; tn < 4; ++tn) {
#pragma unroll
      for (int r = 0; r < 4; ++r) {
        float v = acc[tm][tn][r] * RSCL;
        float dsq = fmaf(-2.0f, v, sqr[tm][r] + sqc[tn]);
        float dst = sqrtf(fmaxf(dsq, 0.f));
        float ev = __builtin_amdgcn_exp2f(fmaf(-L2E, dst, L2E));
        // unique-level diagonal excluded (handled analytically downstream)
        if (diag && tm == tn && (quad * 4 + r) == l15) ev = 0.f;
        rs[r] += ev;
        cs[tn] += ev;
      }
    }
#pragma unroll
    for (int r = 0; r < 4; ++r) {
      float v = rs[r];
      v += __shfl_xor(v, 1, 64);
      v += __shfl_xor(v, 2, 64);
      v += __shfl_xor(v, 4, 64);
      v += __shfl_xor(v, 8, 64);
      if (l15 == 0) rowbuf[warpN][warpM * 64 + tm * 16 + quad * 4 + r] = v;
    }
  }
#pragma unroll
  for (int tn = 0; tn < 4; ++tn) {
    float v = cs[tn];
    v += __shfl_xor(v, 16, 64);
    v += __shfl_xor(v, 32, 64);
    if (quad == 0) colbuf[warpM][warpN * 64 + tn * 16 + l15] = v;
  }
  __syncthreads();

  // rows -> St if cols are text (bx<32) else Ss; cols -> St if rows text
  float* rdst = rowacc + (bx < 32 ? 0 : NU);
  float* cdst = rowacc + (by < 32 ? 0 : NU);
  if (tid < 128) {
    atomicAdd(&rdst[mBase + tid], rowbuf[0][tid] + rowbuf[1][tid]);
  } else if (!diag) {
    int c = tid - 128;
    atomicAdd(&cdst[nBase + c], colbuf[0][c] + colbuf[1][c]);
  }
}

// ---- per-pair fp32 distance + analytic ns + J; atomicAdd into out[0] -------
// 768 blocks x 4 waves, 2 pairs per wave (6144 pairs total).
__global__ __launch_bounds__(256) void loss_kernel(const float* __restrict__ text,
                                                   const float* __restrict__ shape,
                                                   const float* __restrict__ rowacc,
                                                   float* __restrict__ out) {
  __shared__ float part[4];
  const float* St = rowacc;
  const float* Ss = rowacc + NU;
  const int w = threadIdx.x >> 6;
  const int lane = threadIdx.x & 63;
  float jacc = 0.f;
#pragma unroll
  for (int it = 0; it < 2; ++it) {
    int wv = it * 3072 + blockIdx.x * 4 + w;  // 0..6143, exact cover
    const float *a, *b;
    float base, scale;
    if (wv < 2048) {  // tt pair p
      int p = wv;
      a = text + (size_t)(2 * p) * KD;
      b = text + (size_t)(2 * p + 1) * KD;
      base = St[2 * p] + St[2 * p + 1];
      scale = 1.0f / 4096.0f;
    } else {  // st pair
      int p = wv - 2048;
      int u1, u2;
      if (p < 2048) {  // (text_2p, shape_p)
        u1 = 2 * p; u2 = 4096 + p;
        a = text + (size_t)(2 * p) * KD;
        b = shape + (size_t)p * KD;
      } else {         // (shape_s, text_{2s+1})
        int s = p - 2048;
        u1 = 4096 + s; u2 = 2 * s + 1;
        a = shape + (size_t)s * KD;
        b = text + (size_t)(2 * s + 1) * KD;
      }
      float g1 = St[u1] + 2.0f * Ss[u1];
      float g2 = St[u2] + 2.0f * Ss[u2];
      base = g1 + g2 + ECONST;
      scale = 1.0f / 8192.0f;
    }
    // one float4 per lane = whole 256-float row per wave
    float4 va = ((const float4*)a)[lane];
    float4 vb = ((const float4*)b)[lane];
    float d0 = va.x - vb.x, d1 = va.y - vb.y, d2 = va.z - vb.z, d3 = va.w - vb.w;
    float s = d0 * d0 + d1 * d1 + d2 * d2 + d3 * d3;
#pragma unroll
    for (int m = 1; m < 64; m <<= 1) s += __shfl_xor(s, m, 64);
    if (lane == 0) {
      float D = s > 0.f ? sqrtf(s) : 0.f;
      float ns = base - 2.0f * expf(1.0f - D);
      float J = logf(ns) + D;
      jacc += (J > 0.f) ? J * J * scale : 0.f;
    }
  }
  if (lane == 0) part[w] = jacc;
  __syncthreads();
  if (threadIdx.x == 0) atomicAdd(out, part[0] + part[1] + part[2] + part[3]);
}

extern "C" void kernel_launch(void* const* d_in, const int* in_sizes, int n_in,
                              void* d_out, int out_size, void* d_ws, size_t ws_size,
                              hipStream_t stream) {
  const float* text = (const float*)d_in[0];
  const float* shape = (const float*)d_in[1];
  float* out = (float*)d_out;

  char* ws = (char*)d_ws;
  __bf16* Xu = (__bf16*)ws;                                // 3 MB
  float* sq = (float*)(ws + (size_t)NU * KD * 2);          // 24 KB
  float* rowacc = sq + NU;                                 // 48 KB (St ++ Ss)

  prep_kernel<<<NU / 4, 256, 0, stream>>>(text, shape, Xu, sq, rowacc, out, out_size);
  egemm_tri_kernel<<<TU, 256, 0, stream>>>(Xu, sq, rowacc);
  loss_kernel<<<768, 256, 0, stream>>>(text, shape, rowacc, out);
}

// Round 6
// 100.369 us; speedup vs baseline: 1.2363x; 1.2363x over previous
//
#include <hip/hip_runtime.h>
#include <hip/hip_bf16.h>
#include <math.h>

// ---------------------------------------------------------------------------
// Metric loss (lifted structure) on MI355X — R9: counted-vmcnt egemm pipeline.
// R8 measurement: Gram-pass marginal cost 11.8us; 3x-egemm profile shows
// MfmaUtil 15 / VALU 27 / ~60% idle at 28% occupancy -> K-loop is stalled on
// the per-step vmcnt(0) drain (full L2 latency exposed every step).
// R9: 3-buffer LDS, 2-step-deep prefetch, s_waitcnt vmcnt(4) in steady state
// (T4: never drain to 0 mid-loop). Safety: barrier(t) publishes that every
// wave's step-t loads landed (each passed its own vmcnt(4)); stage(t+2)
// writes buf (t+2)%3, disjoint from buf t%3 (read now) and (t+1)%3 (in
// flight); step t-1 ds_reads are consumed before barrier(t), so the mod-3
// reuse is race-free. Loop fully unrolled (immediates need constants).
// GRAM_REPS reverted to 1. prep/loss unchanged from R7.
// ---------------------------------------------------------------------------

typedef __bf16 bf16x8 __attribute__((ext_vector_type(8)));
typedef float floatx4 __attribute__((ext_vector_type(4)));

#define KD 256
#define NU 6144
#define NBU 48
#define TU (NBU * (NBU + 1) / 2) /* 1176 */
#define BM 128
#define BK 32
#define KSTEPS (KD / BK) /* 8 */
#define ECONST 2.718281828459045f

// logical (row r, 16B k-slot q) -> bf16 element index in swizzled LDS tile
#define LSLOT(r, q) ((((r) * 4 + ((q) ^ (((r) >> 1) & 3)))) * 8)

__device__ __forceinline__ void gload_lds16(const void* g, void* l) {
  __builtin_amdgcn_global_load_lds((const __attribute__((address_space(1))) unsigned int*)g,
                                   (__attribute__((address_space(3))) unsigned int*)l,
                                   16, 0, 0);
}

// ---- prep: bf16 convert unique rows, row sq from bf16; zero accums + out ---
__global__ __launch_bounds__(256) void prep_kernel(const float* __restrict__ text,
                                                   const float* __restrict__ shape,
                                                   __bf16* __restrict__ Xu,
                                                   float* __restrict__ sq,
                                                   float* __restrict__ rowacc,
                                                   float* __restrict__ out, int out_n) {
  int gt = blockIdx.x * 256 + threadIdx.x;
  if (gt < 2 * NU) rowacc[gt] = 0.f;  // St ++ Ss contiguous
  if (gt < out_n) out[gt] = 0.f;      // loss kernel atomicAdds into out[0]
  int wave = gt >> 6;                 // one wave per unique row, 0..6143
  int lane = gt & 63;
  const float* src = (wave < 4096) ? (text + (size_t)wave * KD)
                                   : (shape + (size_t)(wave - 4096) * KD);
  // one float4 per lane = the whole 256-float row per wave
  float4 v = ((const float4*)src)[lane];
  __bf16 h0 = (__bf16)v.x, h1 = (__bf16)v.y, h2 = (__bf16)v.z, h3 = (__bf16)v.w;
  union { __bf16 h[4]; ushort2 u2[2]; } pk;
  pk.h[0] = h0; pk.h[1] = h1; pk.h[2] = h2; pk.h[3] = h3;
  ((ushort2*)(Xu + (size_t)wave * KD))[lane * 2] = pk.u2[0];
  ((ushort2*)(Xu + (size_t)wave * KD))[lane * 2 + 1] = pk.u2[1];
  // square the ROUNDED values (consistency with MFMA G)
  float f0 = (float)h0, f1 = (float)h1, f2 = (float)h2, f3 = (float)h3;
  float s = f0 * f0 + f1 * f1 + f2 * f2 + f3 * f3;
#pragma unroll
  for (int m = 1; m < 64; m <<= 1) s += __shfl_xor(s, m, 64);
  if (lane == 0) sq[wave] = s;
}

// ---- triangular Gram + E + diag-free row/col partial sums ------------------
// (256,3): 170-VGPR cap; LDS 50KB -> 3 blocks/CU.
__global__ __launch_bounds__(256, 3) void egemm_tri_kernel(
    const __bf16* __restrict__ X, const float* __restrict__ sq,
    float* __restrict__ rowacc) {  // [0,NU)=St, [NU,2NU)=Ss
  __shared__ __align__(16) __bf16 As[3][BM * BK];
  __shared__ __align__(16) __bf16 Bs[3][BM * BK];
  __shared__ float rowbuf[2][128];
  __shared__ float colbuf[2][128];

  // triangular decode: by >= bx
  int t = blockIdx.x;
  int by = (int)((sqrtf(8.0f * (float)t + 1.0f) - 1.0f) * 0.5f);
  while ((by + 1) * (by + 2) / 2 <= t) ++by;
  while (by * (by + 1) / 2 > t) --by;
  const int bx = t - by * (by + 1) / 2;

  const int mBase = by * BM;  // rows (mBase >= nBase)
  const int nBase = bx * BM;  // cols
  const bool diag = (by == bx);

  const int tid = threadIdx.x;
  const int lane = tid & 63;
  const int w = tid >> 6;  // 2x2 wave grid of 64x64 tiles
  const int warpM = w >> 1, warpN = w & 1;
  const int quad = lane >> 4;
  const int l15 = lane & 15;

  floatx4 acc[4][4] = {};

  // staging: chunk c (16 rows, 1KB); lane L -> row 16c+(L>>2), swizzled k-slot
  const int sRow = lane >> 2;
  const int sCol = (((lane & 3) ^ ((lane >> 3) & 3))) * 8;

  // counted-vmcnt pipeline: 3 buffers, 2 steps prefetched ahead; per wave
  // 4 gload_lds per stage -> steady state 8 outstanding, wait vmcnt(4) so
  // only the CURRENT step's loads are drained (next step's stay in flight).
#define STAGE(b, kt)                                                                   \
  {                                                                                    \
    _Pragma("unroll") for (int h = 0; h < 2; ++h) {                                    \
      int c = h * 4 + w;                                                               \
      gload_lds16(X + (size_t)(mBase + c * 16 + sRow) * KD + (kt) + sCol,              \
                  &As[b][c * 512]);                                                    \
      gload_lds16(X + (size_t)(nBase + c * 16 + sRow) * KD + (kt) + sCol,              \
                  &Bs[b][c * 512]);                                                    \
    }                                                                                  \
  }

  STAGE(0, 0);
  STAGE(1, BK);
#pragma unroll
  for (int s = 0; s < KSTEPS; ++s) {
    // s < KSTEPS-1: 8 outstanding (steps s, s+1) -> vmcnt(4) drains step s.
    // s == KSTEPS-1: only step s's 4 outstanding -> need vmcnt(0).
    if (s < KSTEPS - 1)
      asm volatile("s_waitcnt vmcnt(4)" ::: "memory");
    else
      asm volatile("s_waitcnt vmcnt(0)" ::: "memory");
    __builtin_amdgcn_s_barrier();
    asm volatile("" ::: "memory");
    if (s + 2 < KSTEPS) STAGE((s + 2) % 3, (s + 2) * BK);

    const int cur = s % 3;
    bf16x8 af[4], bfr[4];
#pragma unroll
    for (int tm = 0; tm < 4; ++tm)
      af[tm] = *(const bf16x8*)&As[cur][LSLOT(warpM * 64 + tm * 16 + l15, quad)];
#pragma unroll
    for (int tn = 0; tn < 4; ++tn)
      bfr[tn] = *(const bf16x8*)&Bs[cur][LSLOT(warpN * 64 + tn * 16 + l15, quad)];
#pragma unroll
    for (int tm = 0; tm < 4; ++tm)
#pragma unroll
      for (int tn = 0; tn < 4; ++tn)
        acc[tm][tn] = __builtin_amdgcn_mfma_f32_16x16x32_bf16(af[tm], bfr[tn], acc[tm][tn], 0, 0, 0);
  }
#undef STAGE

  // ---- epilogue: E = exp(1-D), diag-free row+col sums ----
  const int rbase = mBase + warpM * 64;
  const int cbase = nBase + warpN * 64;
  float sqr[4][4], sqc[4];
#pragma unroll
  for (int tm = 0; tm < 4; ++tm)
#pragma unroll
    for (int r = 0; r < 4; ++r)
      sqr[tm][r] = sq[rbase + tm * 16 + quad * 4 + r];
#pragma unroll
  for (int tn = 0; tn < 4; ++tn)
    sqc[tn] = sq[cbase + tn * 16 + l15];

  const float L2E = 1.44269504088896f;
  float cs[4] = {0.f, 0.f, 0.f, 0.f};
#pragma unroll
  for (int tm = 0; tm < 4; ++tm) {
    float rs[4] = {0.f, 0.f, 0.f, 0.f};
#pragma unroll
    for (int tn = 0; tn < 4; ++tn) {
#pragma unroll
      for (int r = 0; r < 4; ++r) {
        float v = acc[tm][tn][r];
        float dsq = fmaf(-2.0f, v, sqr[tm][r] + sqc[tn]);
        float dst = sqrtf(fmaxf(dsq, 0.f));
        float ev = __builtin_amdgcn_exp2f(fmaf(-L2E, dst, L2E));
        // unique-level diagonal excluded (handled analytically downstream)
        if (diag && tm == tn && (quad * 4 + r) == l15) ev = 0.f;
        rs[r] += ev;
        cs[tn] += ev;
      }
    }
#pragma unroll
    for (int r = 0; r < 4; ++r) {
      float v = rs[r];
      v += __shfl_xor(v, 1, 64);
      v += __shfl_xor(v, 2, 64);
      v += __shfl_xor(v, 4, 64);
      v += __shfl_xor(v, 8, 64);
      if (l15 == 0) rowbuf[warpN][warpM * 64 + tm * 16 + quad * 4 + r] = v;
    }
  }
#pragma unroll
  for (int tn = 0; tn < 4; ++tn) {
    float v = cs[tn];
    v += __shfl_xor(v, 16, 64);
    v += __shfl_xor(v, 32, 64);
    if (quad == 0) colbuf[warpM][warpN * 64 + tn * 16 + l15] = v;
  }
  __syncthreads();

  // rows -> St if cols are text (bx<32) else Ss; cols -> St if rows text
  float* rdst = rowacc + (bx < 32 ? 0 : NU);
  float* cdst = rowacc + (by < 32 ? 0 : NU);
  if (tid < 128) {
    atomicAdd(&rdst[mBase + tid], rowbuf[0][tid] + rowbuf[1][tid]);
  } else if (!diag) {
    int c = tid - 128;
    atomicAdd(&cdst[nBase + c], colbuf[0][c] + colbuf[1][c]);
  }
}

// ---- per-pair fp32 distance + analytic ns + J; atomicAdd into out[0] -------
// 768 blocks x 4 waves, 2 pairs per wave (6144 pairs total).
__global__ __launch_bounds__(256) void loss_kernel(const float* __restrict__ text,
                                                   const float* __restrict__ shape,
                                                   const float* __restrict__ rowacc,
                                                   float* __restrict__ out) {
  __shared__ float part[4];
  const float* St = rowacc;
  const float* Ss = rowacc + NU;
  const int w = threadIdx.x >> 6;
  const int lane = threadIdx.x & 63;
  float jacc = 0.f;
#pragma unroll
  for (int it = 0; it < 2; ++it) {
    int wv = it * 3072 + blockIdx.x * 4 + w;  // 0..6143, exact cover
    const float *a, *b;
    float base, scale;
    if (wv < 2048) {  // tt pair p
      int p = wv;
      a = text + (size_t)(2 * p) * KD;
      b = text + (size_t)(2 * p + 1) * KD;
      base = St[2 * p] + St[2 * p + 1];
      scale = 1.0f / 4096.0f;
    } else {  // st pair
      int p = wv - 2048;
      int u1, u2;
      if (p < 2048) {  // (text_2p, shape_p)
        u1 = 2 * p; u2 = 4096 + p;
        a = text + (size_t)(2 * p) * KD;
        b = shape + (size_t)p * KD;
      } else {         // (shape_s, text_{2s+1})
        int s = p - 2048;
        u1 = 4096 + s; u2 = 2 * s + 1;
        a = shape + (size_t)s * KD;
        b = text + (size_t)(2 * s + 1) * KD;
      }
      float g1 = St[u1] + 2.0f * Ss[u1];
      float g2 = St[u2] + 2.0f * Ss[u2];
      base = g1 + g2 + ECONST;
      scale = 1.0f / 8192.0f;
    }
    // one float4 per lane = whole 256-float row per wave
    float4 va = ((const float4*)a)[lane];
    float4 vb = ((const float4*)b)[lane];
    float d0 = va.x - vb.x, d1 = va.y - vb.y, d2 = va.z - vb.z, d3 = va.w - vb.w;
    float s = d0 * d0 + d1 * d1 + d2 * d2 + d3 * d3;
#pragma unroll
    for (int m = 1; m < 64; m <<= 1) s += __shfl_xor(s, m, 64);
    if (lane == 0) {
      float D = s > 0.f ? sqrtf(s) : 0.f;
      float ns = base - 2.0f * expf(1.0f - D);
      float J = logf(ns) + D;
      jacc += (J > 0.f) ? J * J * scale : 0.f;
    }
  }
  if (lane == 0) part[w] = jacc;
  __syncthreads();
  if (threadIdx.x == 0) atomicAdd(out, part[0] + part[1] + part[2] + part[3]);
}

extern "C" void kernel_launch(void* const* d_in, const int* in_sizes, int n_in,
                              void* d_out, int out_size, void* d_ws, size_t ws_size,
                              hipStream_t stream) {
  const float* text = (const float*)d_in[0];
  const float* shape = (const float*)d_in[1];
  float* out = (float*)d_out;

  char* ws = (char*)d_ws;
  __bf16* Xu = (__bf16*)ws;                                // 3 MB
  float* sq = (float*)(ws + (size_t)NU * KD * 2);          // 24 KB
  float* rowacc = sq + NU;                                 // 48 KB (St ++ Ss)

  prep_kernel<<<NU / 4, 256, 0, stream>>>(text, shape, Xu, sq, rowacc, out, out_size);
  egemm_tri_kernel<<<TU, 256, 0, stream>>>(Xu, sq, rowacc);
  loss_kernel<<<768, 256, 0, stream>>>(text, shape, rowacc, out);
}